// Round 1
// baseline (273.635 us; speedup 1.0000x reference)
//
#include <hip/hip_runtime.h>

// Problem constants (B=8, N=256, DIN=DOUT=EIN=EOUT=64)
#define BN   2048      // B*N
#define NN   256       // N
#define CH   64        // channel dims

typedef __attribute__((ext_vector_type(8))) short short8;   // 8 bf16
typedef __attribute__((ext_vector_type(4))) float fv4;

// fp32 -> bf16 bits, round-to-nearest-even
static __device__ inline short f2bf(float f) {
  unsigned u = __float_as_uint(f);
  u += 0x7FFF + ((u >> 16) & 1);
  return (short)(u >> 16);
}
static __device__ inline short8 cvt8(fv4 a, fv4 b) {
  short8 r;
  r[0] = f2bf(a[0]); r[1] = f2bf(a[1]); r[2] = f2bf(a[2]); r[3] = f2bf(a[3]);
  r[4] = f2bf(b[0]); r[5] = f2bf(b[1]); r[6] = f2bf(b[2]); r[7] = f2bf(b[3]);
  return r;
}

// ---------------------------------------------------------------------------
// Kernel 1: node_x = emb_node@Wn + bn (fp32), rsx = relu(emb_node@Wsn + bsn).
// Unchanged from previous round (small fraction of total time).
// ---------------------------------------------------------------------------
__global__ __launch_bounds__(256) void node_kernel(
    const float* __restrict__ emb_node, const float* __restrict__ Wn,
    const float* __restrict__ bn, const float* __restrict__ Wsn,
    const float* __restrict__ bsn, float* __restrict__ node_x,
    float* __restrict__ rsx) {
  __shared__ float s_emb[4][CH];
  __shared__ float s_Wn[CH * CH];   // 16 KB
  __shared__ float s_Ws[CH * CH];   // 16 KB
  const int tid = threadIdx.x;
  const int r = tid >> 6;
  const int c = tid & 63;
  const int row = blockIdx.x * 4 + r;
#pragma unroll
  for (int i = 0; i < 4; ++i) {
    *(fv4*)&s_Wn[(i * 256 + tid) * 4] = *(const fv4*)&Wn[(i * 256 + tid) * 4];
    *(fv4*)&s_Ws[(i * 256 + tid) * 4] = *(const fv4*)&Wsn[(i * 256 + tid) * 4];
  }
  s_emb[r][c] = emb_node[row * CH + c];
  __syncthreads();
  float a1 = bn[c], a2 = bsn[c];
#pragma unroll
  for (int k = 0; k < CH; ++k) {
    const float e = s_emb[r][k];          // wave-uniform broadcast
    a1 = fmaf(e, s_Wn[k * CH + c], a1);
    a2 = fmaf(e, s_Ws[k * CH + c], a2);
  }
  node_x[row * CH + c] = a1;
  rsx[row * CH + c] = fmaxf(a2, 0.0f);
}

// ---------------------------------------------------------------------------
// Kernel 2 (restructured, barrier-free main loop):
//   Block per (b,i). Wave w owns rows [64w, 64w+64) and ALL 64 output cols.
//   All of We lives in registers (4 col-tiles x 2 K-halves of bf16 frags).
//   A-fragments are built directly from global fv4 loads (lane l15 -> row,
//   quad*8 -> k slice; identical mapping to the verified LDS path), so the
//   main loop has NO LDS, NO barriers, and a 2-tile register pipeline
//   (8 dwordx4 = 128 B/thread in flight).
//   Epilogue per 16-row tile: ex = acc + be (bias folded into MFMA C-in),
//   nontemporal store of relu(ex), agg[c] += A[j]*ex*node_x[j,c].
//   End: quad shfl-reduce, 1KB-LDS cross-wave reduce, node_out write.
// ---------------------------------------------------------------------------
__global__ __launch_bounds__(256, 4) void edge_mfma_kernel(
    const float* __restrict__ A, const float* __restrict__ emb_edge,
    const float* __restrict__ We, const float* __restrict__ be,
    const float* __restrict__ node_x, const float* __restrict__ rsx,
    float* __restrict__ node_out, float* __restrict__ edge_out) {
  const int bi   = blockIdx.x;         // b*N + i
  const int b    = bi >> 8;
  const int tid  = threadIdx.x;
  const int lane = tid & 63;
  const int wave = tid >> 6;           // 0..3 -> row strip [64w, 64w+64)
  const int l15  = lane & 15;
  const int quad = lane >> 4;

  __shared__ float s_red[4][CH];       // 1 KB cross-wave agg reduce

  // B fragments: full We in VGPRs. bf[tc][h]: k = h*32 + quad*8 + j,
  // col c = tc*16 + l15.  32 VGPRs total.
  short8 bf[4][2];
  float  beL[4];
#pragma unroll
  for (int tc = 0; tc < 4; ++tc) {
    const int c = tc * 16 + l15;
    beL[tc] = be[c];
#pragma unroll
    for (int h = 0; h < 2; ++h)
#pragma unroll
      for (int j = 0; j < 8; ++j)
        bf[tc][h][j] = f2bf(We[(h * 32 + quad * 8 + j) * CH + c]);
  }

  const float* __restrict__ ee = emb_edge + (size_t)bi * NN * CH;
  float*       __restrict__ eo = edge_out + (size_t)bi * NN * CH;
  const float* __restrict__ nx = node_x + (size_t)b * NN * CH;
  const float* __restrict__ Ar = A + (size_t)bi * NN;

  const int wbase = wave * 64;
  float agg[4] = {0.f, 0.f, 0.f, 0.f};

  fv4 x0, x1, x2, x3, y0, y1, y2, y3;

  // A-fragment loads for 16-row tile T: row = wbase+T*16+l15,
  // k slices [quad*8, +8) and [32+quad*8, +8)  -> 4x fv4 (64 B/thread).
#define LOADT(T, A0, A1, A2, A3)                                             \
  {                                                                          \
    const float* rp = ee + (wbase + (T) * 16 + l15) * CH + quad * 8;         \
    A0 = *(const fv4*)rp;        A1 = *(const fv4*)(rp + 4);                 \
    A2 = *(const fv4*)(rp + 32); A3 = *(const fv4*)(rp + 36);                \
  }

#define COMPT(T, A0, A1, A2, A3)                                             \
  {                                                                          \
    const int j0 = wbase + (T) * 16;                                         \
    const int rb = j0 + quad * 4;                                            \
    const fv4 av = *(const fv4*)(Ar + rb);                                   \
    const float* nxp = nx + rb * CH + l15;                                   \
    float nxv[4][4];                                                         \
    _Pragma("unroll") for (int tc = 0; tc < 4; ++tc)                         \
      _Pragma("unroll") for (int r = 0; r < 4; ++r)                          \
        nxv[tc][r] = nxp[r * CH + tc * 16];   /* L2/L3-resident */           \
    const short8 af0 = cvt8(A0, A1);                                         \
    const short8 af1 = cvt8(A2, A3);                                         \
    _Pragma("unroll") for (int tc = 0; tc < 4; ++tc) {                       \
      fv4 acc = {beL[tc], beL[tc], beL[tc], beL[tc]};  /* bias as C-in */    \
      acc = __builtin_amdgcn_mfma_f32_16x16x32_bf16(af0, bf[tc][0], acc, 0, 0, 0); \
      acc = __builtin_amdgcn_mfma_f32_16x16x32_bf16(af1, bf[tc][1], acc, 0, 0, 0); \
      _Pragma("unroll") for (int r = 0; r < 4; ++r) {                        \
        const int row = rb + r;                                              \
        const float ex = acc[r];                       /* pre-relu edge_x */ \
        __builtin_nontemporal_store(fmaxf(ex, 0.f),                          \
                                    eo + row * CH + tc * 16 + l15);          \
        agg[tc] = fmaf(av[r] * ex, nxv[tc][r], agg[tc]);                     \
      }                                                                      \
    }                                                                        \
  }

  // 2-deep software pipeline over the wave's 4 row-tiles (no barriers).
  LOADT(0, x0, x1, x2, x3);
  LOADT(1, y0, y1, y2, y3);
  COMPT(0, x0, x1, x2, x3);
  LOADT(2, x0, x1, x2, x3);
  COMPT(1, y0, y1, y2, y3);
  LOADT(3, y0, y1, y2, y3);
  COMPT(2, x0, x1, x2, x3);
  COMPT(3, y0, y1, y2, y3);

#undef LOADT
#undef COMPT

  // agg[tc] currently: sum over this thread's rows (4 per tile x 4 tiles)
  // for col c = tc*16 + l15.  Reduce across quads (same col, lane^16/^32),
  // then across waves via LDS.
#pragma unroll
  for (int tc = 0; tc < 4; ++tc) {
    agg[tc] += __shfl_xor(agg[tc], 16, 64);
    agg[tc] += __shfl_xor(agg[tc], 32, 64);
  }
  if (quad == 0) {
#pragma unroll
    for (int tc = 0; tc < 4; ++tc) s_red[wave][tc * 16 + l15] = agg[tc];
  }
  __syncthreads();
  if (tid < CH) {
    const float s =
        s_red[0][tid] + s_red[1][tid] + s_red[2][tid] + s_red[3][tid];
    node_out[(size_t)bi * CH + tid] =
        fmaxf(s, 0.f) + rsx[(size_t)bi * CH + tid];
  }
}

// ---------------------------------------------------------------------------
extern "C" void kernel_launch(void* const* d_in, const int* in_sizes, int n_in,
                              void* d_out, int out_size, void* d_ws, size_t ws_size,
                              hipStream_t stream) {
  const float* A        = (const float*)d_in[0];  // [8,256,256]
  const float* emb_node = (const float*)d_in[1];  // [8,256,64]
  const float* emb_edge = (const float*)d_in[2];  // [8,256,256,64]
  const float* Wn       = (const float*)d_in[3];  // [64,64]
  const float* bn       = (const float*)d_in[4];  // [64]
  const float* Wsn      = (const float*)d_in[5];  // [64,64]
  const float* bsn      = (const float*)d_in[6];  // [64]
  const float* We       = (const float*)d_in[7];  // [64,64]
  const float* be       = (const float*)d_in[8];  // [64]

  float* node_out = (float*)d_out;                     // [2048,64]
  float* edge_out = (float*)d_out + (size_t)BN * CH;   // [2048,256,64]

  float* node_x = (float*)d_ws;                        // [2048,64] fp32
  float* rsx    = (float*)d_ws + (size_t)BN * CH;      // [2048,64] fp32

  hipLaunchKernelGGL(node_kernel, dim3(BN / 4), dim3(256), 0, stream,
                     emb_node, Wn, bn, Wsn, bsn, node_x, rsx);
  hipLaunchKernelGGL(edge_mfma_kernel, dim3(BN), dim3(256), 0, stream,
                     A, emb_edge, We, be, node_x, rsx, node_out, edge_out);
}

// Round 2
// 260.123 us; speedup vs baseline: 1.0519x; 1.0519x over previous
//
#include <hip/hip_runtime.h>

// Problem constants (B=8, N=256, DIN=DOUT=EIN=EOUT=64)
#define BN   2048      // B*N
#define NN   256       // N
#define CH   64        // channel dims
#define RPC  32        // rows per staged chunk
#define NCHK 8         // chunks per block (256/32)
#define LDST 88        // LDS row stride in bf16 elems (176 B)

typedef __attribute__((ext_vector_type(8))) short short8;   // 8 bf16
typedef __attribute__((ext_vector_type(4))) short short4v;  // 4 bf16
typedef __attribute__((ext_vector_type(4))) float fv4;

// fp32 -> bf16 bits, round-to-nearest-even
static __device__ inline short f2bf(float f) {
  unsigned u = __float_as_uint(f);
  u += 0x7FFF + ((u >> 16) & 1);
  return (short)(u >> 16);
}
static __device__ inline short4v cvt4(fv4 v) {
  short4v r;
  r[0] = f2bf(v[0]); r[1] = f2bf(v[1]); r[2] = f2bf(v[2]); r[3] = f2bf(v[3]);
  return r;
}

// ---------------------------------------------------------------------------
// Kernel 1: node_x = emb_node@Wn + bn (fp32), rsx = relu(emb_node@Wsn + bsn).
// ---------------------------------------------------------------------------
__global__ __launch_bounds__(256) void node_kernel(
    const float* __restrict__ emb_node, const float* __restrict__ Wn,
    const float* __restrict__ bn, const float* __restrict__ Wsn,
    const float* __restrict__ bsn, float* __restrict__ node_x,
    float* __restrict__ rsx) {
  __shared__ float s_emb[4][CH];
  __shared__ float s_Wn[CH * CH];   // 16 KB
  __shared__ float s_Ws[CH * CH];   // 16 KB
  const int tid = threadIdx.x;
  const int r = tid >> 6;
  const int c = tid & 63;
  const int row = blockIdx.x * 4 + r;
#pragma unroll
  for (int i = 0; i < 4; ++i) {
    *(fv4*)&s_Wn[(i * 256 + tid) * 4] = *(const fv4*)&Wn[(i * 256 + tid) * 4];
    *(fv4*)&s_Ws[(i * 256 + tid) * 4] = *(const fv4*)&Wsn[(i * 256 + tid) * 4];
  }
  s_emb[r][c] = emb_node[row * CH + c];
  __syncthreads();
  float a1 = bn[c], a2 = bsn[c];
#pragma unroll
  for (int k = 0; k < CH; ++k) {
    const float e = s_emb[r][k];          // wave-uniform broadcast
    a1 = fmaf(e, s_Wn[k * CH + c], a1);
    a2 = fmaf(e, s_Ws[k * CH + c], a2);
  }
  node_x[row * CH + c] = a1;
  rsx[row * CH + c] = fmaxf(a2, 0.0f);
}

// ---------------------------------------------------------------------------
// Kernel 2: round-0 structure (col-strip waves, coalesced LDS staging) with
// every vmcnt-drain removed:
//  - nx(ch) loads hoisted one chunk early; issue order == consume order, so
//    counted vmcnt waits never drain the emb prefetch (in-order counter).
//  - 3-deep emb prefetch in registers (chunk ch+3 issued at iter ch).
//  - raw s_barrier with only lgkmcnt(0) (vmem stays in flight across the
//    barrier; __syncthreads would emit vmcnt(0)).
//  - plain stores (nt stores regressed WRITE_SIZE in round 1).
// Wave w owns cols [16w,16w+16). C/D: col=lane&15, row=quad*4+reg (m89).
// ---------------------------------------------------------------------------
__global__ __launch_bounds__(256, 4) void edge_mfma_kernel(
    const float* __restrict__ A, const float* __restrict__ emb_edge,
    const float* __restrict__ We, const float* __restrict__ be,
    const float* __restrict__ node_x, const float* __restrict__ rsx,
    float* __restrict__ node_out, float* __restrict__ edge_out) {
  const int bi   = blockIdx.x;         // b*N + i
  const int b    = bi >> 8;
  const int tid  = threadIdx.x;
  const int lane = tid & 63;
  const int wave = tid >> 6;           // 0..3 -> col tile
  const int l15  = lane & 15;
  const int quad = lane >> 4;
  const int c    = wave * 16 + l15;

  __shared__ __align__(16) short sbuf[2][RPC * LDST];  // 2 x 5632 B bf16
  __shared__ float s_A[NN];                            // 1 KB

  const float* __restrict__ ee = emb_edge + (size_t)bi * NN * CH;
  float*       __restrict__ eo = edge_out + (size_t)bi * NN * CH;
  const float* __restrict__ nx = node_x + (size_t)b * NN * CH;

  // ---- prologue: vmem issue order == need order ----
  // A row (needed first, via LDS), We frags, then emb(0), nx(0), emb(1,2).
  const float aval = A[(size_t)bi * NN + tid];
  float wraw[16];
#pragma unroll
  for (int h = 0; h < 2; ++h)
#pragma unroll
    for (int j = 0; j < 8; ++j)
      wraw[h * 8 + j] = We[(h * 32 + quad * 8 + j) * CH + c];
  const float bias = be[c];

  const int srow = tid >> 4;
  const int kcol = (tid & 15) * 4;

  fv4 st[3][2];                         // 3-deep chunk prefetch (24 VGPR)
  st[0][0] = *(const fv4*)(ee + tid * 4);
  st[0][1] = *(const fv4*)(ee + 1024 + tid * 4);

  float nxv[2][8];                      // nx double-buffer (16 VGPR)
#pragma unroll
  for (int h = 0; h < 2; ++h)
#pragma unroll
    for (int r = 0; r < 4; ++r)
      nxv[0][h * 4 + r] = nx[(h * 16 + quad * 4 + r) * CH + c];

  st[1][0] = *(const fv4*)(ee + 2048 + tid * 4);
  st[1][1] = *(const fv4*)(ee + 3072 + tid * 4);
  st[2][0] = *(const fv4*)(ee + 4096 + tid * 4);
  st[2][1] = *(const fv4*)(ee + 5120 + tid * 4);

  s_A[tid] = aval;                      // waits only the A load (oldest)

  short8 bfrag[2];                      // waits only the We loads
#pragma unroll
  for (int h = 0; h < 2; ++h)
#pragma unroll
    for (int j = 0; j < 8; ++j)
      bfrag[h][j] = f2bf(wraw[h * 8 + j]);

  // chunk 0 -> LDS (waits emb(0); nx(0), emb(1), emb(2) stay in flight)
  *(short4v*)&sbuf[0][srow * LDST + kcol] = cvt4(st[0][0]);
  *(short4v*)&sbuf[0][(16 + srow) * LDST + kcol] = cvt4(st[0][1]);

  float agg = 0.0f;

#pragma unroll
  for (int ch = 0; ch < NCHK; ++ch) {
    const int pb = ch & 1;

    // issue nx(ch+1) (consumed next iter; older than emb(ch+3) below)
    if (ch + 1 < NCHK) {
#pragma unroll
      for (int h = 0; h < 2; ++h)
#pragma unroll
        for (int r = 0; r < 4; ++r)
          nxv[(ch + 1) & 1][h * 4 + r] =
              nx[((ch + 1) * RPC + h * 16 + quad * 4 + r) * CH + c];
    }
    // issue emb(ch+3) into the slot chunk ch vacated last iter
    if (ch + 3 < NCHK) {
      const float* cb = ee + (ch + 3) * (RPC * CH);
      st[ch % 3][0] = *(const fv4*)(cb + tid * 4);
      st[ch % 3][1] = *(const fv4*)(cb + 1024 + tid * 4);
    }

    // barrier WITHOUT vmcnt drain: only DS ops must settle for sbuf[pb]
    asm volatile("s_waitcnt lgkmcnt(0)" ::: "memory");
    __builtin_amdgcn_s_barrier();

#pragma unroll
    for (int h = 0; h < 2; ++h) {
      const int j0l = h * 16;
      const int j0  = ch * RPC + j0l;
      const fv4 av = *(const fv4*)&s_A[j0 + quad * 4];   // LDS broadcast
      const short8 af0 =
          *(const short8*)&sbuf[pb][(j0l + l15) * LDST + quad * 8];
      const short8 af1 =
          *(const short8*)&sbuf[pb][(j0l + l15) * LDST + 32 + quad * 8];
      fv4 acc = {bias, bias, bias, bias};                // bias as C-in
      acc = __builtin_amdgcn_mfma_f32_16x16x32_bf16(af0, bfrag[0], acc, 0, 0, 0);
      acc = __builtin_amdgcn_mfma_f32_16x16x32_bf16(af1, bfrag[1], acc, 0, 0, 0);
#pragma unroll
      for (int r = 0; r < 4; ++r) {
        const int row = j0 + quad * 4 + r;
        const float ex = acc[r];                         // pre-relu edge_x
        eo[row * CH + c] = fmaxf(ex, 0.0f);
        agg = fmaf(av[r] * ex, nxv[ch & 1][h * 4 + r], agg);
      }
    }

    // write chunk ch+1 regs -> other LDS buffer (waits only emb(ch+1);
    // nx(ch+1), emb(ch+2), emb(ch+3) are newer and stay in flight)
    if (ch + 1 < NCHK) {
      *(short4v*)&sbuf[pb ^ 1][srow * LDST + kcol] = cvt4(st[(ch + 1) % 3][0]);
      *(short4v*)&sbuf[pb ^ 1][(16 + srow) * LDST + kcol] =
          cvt4(st[(ch + 1) % 3][1]);
    }
  }

  // reduce per-quad partials (same col c at lane^16, lane^32)
  agg += __shfl_xor(agg, 16, 64);
  agg += __shfl_xor(agg, 32, 64);
  if (quad == 0) {
    node_out[(size_t)bi * CH + c] =
        fmaxf(agg, 0.0f) + rsx[(size_t)bi * CH + c];
  }
}

// ---------------------------------------------------------------------------
extern "C" void kernel_launch(void* const* d_in, const int* in_sizes, int n_in,
                              void* d_out, int out_size, void* d_ws, size_t ws_size,
                              hipStream_t stream) {
  const float* A        = (const float*)d_in[0];  // [8,256,256]
  const float* emb_node = (const float*)d_in[1];  // [8,256,64]
  const float* emb_edge = (const float*)d_in[2];  // [8,256,256,64]
  const float* Wn       = (const float*)d_in[3];  // [64,64]
  const float* bn       = (const float*)d_in[4];  // [64]
  const float* Wsn      = (const float*)d_in[5];  // [64,64]
  const float* bsn      = (const float*)d_in[6];  // [64]
  const float* We       = (const float*)d_in[7];  // [64,64]
  const float* be       = (const float*)d_in[8];  // [64]

  float* node_out = (float*)d_out;                     // [2048,64]
  float* edge_out = (float*)d_out + (size_t)BN * CH;   // [2048,256,64]

  float* node_x = (float*)d_ws;                        // [2048,64] fp32
  float* rsx    = (float*)d_ws + (size_t)BN * CH;      // [2048,64] fp32

  hipLaunchKernelGGL(node_kernel, dim3(BN / 4), dim3(256), 0, stream,
                     emb_node, Wn, bn, Wsn, bsn, node_x, rsx);
  hipLaunchKernelGGL(edge_mfma_kernel, dim3(BN), dim3(256), 0, stream,
                     A, emb_edge, We, be, node_x, rsx, node_out, edge_out);
}

// Round 4
// 258.156 us; speedup vs baseline: 1.0600x; 1.0076x over previous
//
#include <hip/hip_runtime.h>

// Problem constants (B=8, N=256, DIN=DOUT=EIN=EOUT=64)
#define BN   2048      // B*N
#define NN   256       // N
#define CH   64        // channel dims
#define NCHK 8         // 32-row chunks per block (256/32)

typedef __attribute__((ext_vector_type(8))) short short8;   // 8 bf16
typedef __attribute__((ext_vector_type(4))) float fv4;

// fp32 -> bf16 bits, round-to-nearest-even (We prologue only)
static __device__ inline short f2bf(float f) {
  unsigned u = __float_as_uint(f);
  u += 0x7FFF + ((u >> 16) & 1);
  return (short)(u >> 16);
}

// 8 fp32 -> short8 bf16 via packed cvt (RNE), 4 instrs
static __device__ inline short8 cvt_frag(fv4 a, fv4 b) {
  union { short8 s; unsigned u[4]; } r;
  asm("v_cvt_pk_bf16_f32 %0, %1, %2" : "=v"(r.u[0]) : "v"(a[0]), "v"(a[1]));
  asm("v_cvt_pk_bf16_f32 %0, %1, %2" : "=v"(r.u[1]) : "v"(a[2]), "v"(a[3]));
  asm("v_cvt_pk_bf16_f32 %0, %1, %2" : "=v"(r.u[2]) : "v"(b[0]), "v"(b[1]));
  asm("v_cvt_pk_bf16_f32 %0, %1, %2" : "=v"(r.u[3]) : "v"(b[2]), "v"(b[3]));
  return r.s;
}

// global -> LDS DMA, 16B per lane. LDS dest = wave-uniform base + lane*16;
// global src is PER-LANE (pre-swizzled for bank-conflict-free reads, m173).
#define GLOAD16(gp, lp)                                                        \
  __builtin_amdgcn_global_load_lds(                                            \
      (const __attribute__((address_space(1))) unsigned*)(gp),                 \
      (__attribute__((address_space(3))) unsigned*)(lp), 16, 0, 0)

#define WAITV(N) asm volatile("s_waitcnt vmcnt(" #N ")" ::: "memory")

// ---------------------------------------------------------------------------
// Kernel 1: node_x = emb_node@Wn + bn (fp32), rsx = relu(emb_node@Wsn + bsn).
// ---------------------------------------------------------------------------
__global__ __launch_bounds__(256) void node_kernel(
    const float* __restrict__ emb_node, const float* __restrict__ Wn,
    const float* __restrict__ bn, const float* __restrict__ Wsn,
    const float* __restrict__ bsn, float* __restrict__ node_x,
    float* __restrict__ rsx) {
  __shared__ float s_emb[4][CH];
  __shared__ float s_Wn[CH * CH];   // 16 KB
  __shared__ float s_Ws[CH * CH];   // 16 KB
  const int tid = threadIdx.x;
  const int r = tid >> 6;
  const int c = tid & 63;
  const int row = blockIdx.x * 4 + r;
#pragma unroll
  for (int i = 0; i < 4; ++i) {
    *(fv4*)&s_Wn[(i * 256 + tid) * 4] = *(const fv4*)&Wn[(i * 256 + tid) * 4];
    *(fv4*)&s_Ws[(i * 256 + tid) * 4] = *(const fv4*)&Wsn[(i * 256 + tid) * 4];
  }
  s_emb[r][c] = emb_node[row * CH + c];
  __syncthreads();
  float a1 = bn[c], a2 = bsn[c];
#pragma unroll
  for (int k = 0; k < CH; ++k) {
    const float e = s_emb[r][k];          // wave-uniform broadcast
    a1 = fmaf(e, s_Wn[k * CH + c], a1);
    a2 = fmaf(e, s_Ws[k * CH + c], a2);
  }
  node_x[row * CH + c] = a1;
  rsx[row * CH + c] = fmaxf(a2, 0.0f);
}

// ---------------------------------------------------------------------------
// Kernel 2: all bulk streams staged via global_load_lds (zero staging VGPRs
// -> compiler cannot sink/collapse the pipeline). fp32 in LDS; bf16 cvt at
// fragment-read time (cvt_pk; VALU has 90% headroom). 3-buffer rotation,
// prefetch distance 2, raw s_barrier with COUNTED vmcnt (never 0 in loop;
// vmcnt retires in order, so interleaved eo stores can't under-drain).
// 16B XOR source-swizzle (linear LDS dest, swizzled per-lane global src)
// makes MFMA frag reads and nx gathers conflict-free.
// A row staged once via plain load + ds_write (single writer), lgkmcnt(0)
// before the first barrier.
// Wave w owns cols [16w,16w+16). C/D: col=lane&15, row=quad*4+reg (m89).
// ---------------------------------------------------------------------------
__global__ __launch_bounds__(256, 4) void edge_mfma_kernel(
    const float* __restrict__ A, const float* __restrict__ emb_edge,
    const float* __restrict__ We, const float* __restrict__ be,
    const float* __restrict__ node_x, const float* __restrict__ rsx,
    float* __restrict__ node_out, float* __restrict__ edge_out) {
  const int bi   = blockIdx.x;         // b*N + i
  const int b    = bi >> 8;
  const int tid  = threadIdx.x;
  const int lane = tid & 63;
  const int wave = tid >> 6;           // 0..3 -> col tile
  const int l15  = lane & 15;
  const int quad = lane >> 4;
  const int c    = wave * 16 + l15;

  // 3-deep chunk buffers: 32 rows x 64 fp32 = 8 KB each
  __shared__ __align__(16) float s_e[3][2048];   // emb_edge (swizzled)
  __shared__ __align__(16) float s_n[3][2048];   // node_x   (swizzled)
  __shared__ __align__(16) float s_Af[NN];       // A row (linear)

  const float* __restrict__ ee = emb_edge + (size_t)bi * NN * CH;
  float*       __restrict__ eo = edge_out + (size_t)bi * NN * CH;
  const float* __restrict__ nx = node_x + (size_t)b * NN * CH;

  // ---- A row (plain load; its wait drains only itself, issued first) ----
  const float aval = A[(size_t)bi * NN + tid];
  s_Af[tid] = aval;

  // ---- We fragments + bias (vector loads, drained by use before DMA) ----
  short8 bfrag[2];
#pragma unroll
  for (int h = 0; h < 2; ++h)
#pragma unroll
    for (int j = 0; j < 8; ++j)
      bfrag[h][j] = f2bf(We[(h * 32 + quad * 8 + j) * CH + c]);
  const float bias = be[c];

  // ---- precomputed per-lane offsets ----
  // staging: lane covers LDS bytes o = wave*2048 + s*1024 + lane*16;
  // row = o>>8, ib = o&255; swizzled src = row*256 + (ib ^ ((row&15)<<4))
  const int rowA = wave * 8 + (lane >> 4);
  const int rowB = rowA + 4;
  const int ibq  = (lane & 15) * 16;
  const int offA = rowA * 256 + (ibq ^ ((rowA & 15) << 4));
  const int offB = rowB * 256 + (ibq ^ ((rowB & 15) << 4));
  // MFMA A-frag reads: rr = h*16+l15 -> rr&15 = l15 for both h
  const int swz = l15 << 4;
  const int o0 = (quad * 32) ^ swz;          // k = quad*8 .. +3
  const int o1 = (quad * 32 + 16) ^ swz;     // k = quad*8+4 .. +7
  const int o2 = (128 + quad * 32) ^ swz;    // k = 32+quad*8 ..
  const int o3 = (144 + quad * 32) ^ swz;
  // nx gathers: local row quad*4+r (h adds 4096B); col c
  int nxo[4];
#pragma unroll
  for (int r = 0; r < 4; ++r)
    nxo[r] = (quad * 4 + r) * 256 + ((c * 4) ^ ((quad * 4 + r) << 4));

#define STAGE(T, D)                                                            \
  {                                                                            \
    const char* eb_ = (const char*)ee + (T) * 8192;                            \
    const char* nb_ = (const char*)nx + (T) * 8192;                            \
    GLOAD16(eb_ + offA, (char*)&s_e[(D)][0] + wave * 2048);                    \
    GLOAD16(eb_ + offB, (char*)&s_e[(D)][0] + wave * 2048 + 1024);             \
    GLOAD16(nb_ + offA, (char*)&s_n[(D)][0] + wave * 2048);                    \
    GLOAD16(nb_ + offB, (char*)&s_n[(D)][0] + wave * 2048 + 1024);             \
  }

  STAGE(0, 0)
  STAGE(1, 1)

  float agg = 0.0f;

#define COMPUTE(CHK, D)                                                        \
  {                                                                            \
    _Pragma("unroll") for (int h = 0; h < 2; ++h) {                            \
      const char* eb_ = (const char*)&s_e[(D)][0] + (h * 16 + l15) * 256;      \
      const fv4 a0 = *(const fv4*)(eb_ + o0);                                  \
      const fv4 a1 = *(const fv4*)(eb_ + o1);                                  \
      const fv4 a2 = *(const fv4*)(eb_ + o2);                                  \
      const fv4 a3 = *(const fv4*)(eb_ + o3);                                  \
      const short8 af0 = cvt_frag(a0, a1);                                     \
      const short8 af1 = cvt_frag(a2, a3);                                     \
      fv4 acc = {bias, bias, bias, bias};                                      \
      acc = __builtin_amdgcn_mfma_f32_16x16x32_bf16(af0, bfrag[0], acc, 0,0,0);\
      acc = __builtin_amdgcn_mfma_f32_16x16x32_bf16(af1, bfrag[1], acc, 0,0,0);\
      const int j0 = (CHK) * 32 + h * 16;                                      \
      const fv4 av = *(const fv4*)&s_Af[j0 + quad * 4];                        \
      const char* nb_ = (const char*)&s_n[(D)][0] + h * 4096;                  \
      _Pragma("unroll") for (int r = 0; r < 4; ++r) {                          \
        const float nxv = *(const float*)(nb_ + nxo[r]);                       \
        const int row = j0 + quad * 4 + r;                                     \
        const float ex = acc[r];                   /* pre-relu edge_x */       \
        eo[row * CH + c] = fmaxf(ex, 0.0f);                                    \
        agg = fmaf(av[r] * ex, nxv, agg);                                      \
      }                                                                        \
    }                                                                          \
  }

  // iteration = wait(own chunk DMA) ; barrier(all waves) ; stage k+2 ;
  // compute k.  vmcnt retires in order -> counts below are exact.
#define ITER(CHK, NW, PF)                                                      \
  {                                                                            \
    WAITV(NW);                                                                 \
    __builtin_amdgcn_s_barrier();                                              \
    if (PF) STAGE((CHK) + 2, ((CHK) + 2) % 3)                                  \
    asm volatile("" ::: "memory"); /* pin stage above stores */                \
    COMPUTE(CHK, (CHK) % 3)                                                    \
  }

  // first barrier also needs the s_Af ds_write visible
  asm volatile("s_waitcnt vmcnt(4) lgkmcnt(0)" ::: "memory");
  __builtin_amdgcn_s_barrier();
  STAGE(2, 2)
  asm volatile("" ::: "memory");
  COMPUTE(0, 0)

  ITER(1, 12, 1)   // newer than c1: c2(4)+stores0(8)
  ITER(2, 20, 1)   // stores0(8)+c3(4)+stores1(8)
  ITER(3, 20, 1)
  ITER(4, 20, 1)
  ITER(5, 20, 1)
  ITER(6, 20, 0)   // stores4(8)+c7(4)+stores5(8)
  ITER(7, 16, 0)   // stores5(8)+stores6(8)

#undef ITER
#undef COMPUTE
#undef STAGE

  // reduce per-quad partials (same col c at lane^16, lane^32)
  agg += __shfl_xor(agg, 16, 64);
  agg += __shfl_xor(agg, 32, 64);
  if (quad == 0) {
    node_out[(size_t)bi * CH + c] =
        fmaxf(agg, 0.0f) + rsx[(size_t)bi * CH + c];
  }
}

// ---------------------------------------------------------------------------
extern "C" void kernel_launch(void* const* d_in, const int* in_sizes, int n_in,
                              void* d_out, int out_size, void* d_ws, size_t ws_size,
                              hipStream_t stream) {
  const float* A        = (const float*)d_in[0];  // [8,256,256]
  const float* emb_node = (const float*)d_in[1];  // [8,256,64]
  const float* emb_edge = (const float*)d_in[2];  // [8,256,256,64]
  const float* Wn       = (const float*)d_in[3];  // [64,64]
  const float* bn       = (const float*)d_in[4];  // [64]
  const float* Wsn      = (const float*)d_in[5];  // [64,64]
  const float* bsn      = (const float*)d_in[6];  // [64]
  const float* We       = (const float*)d_in[7];  // [64,64]
  const float* be       = (const float*)d_in[8];  // [64]

  float* node_out = (float*)d_out;                     // [2048,64]
  float* edge_out = (float*)d_out + (size_t)BN * CH;   // [2048,256,64]

  float* node_x = (float*)d_ws;                        // [2048,64] fp32
  float* rsx    = (float*)d_ws + (size_t)BN * CH;      // [2048,64] fp32

  hipLaunchKernelGGL(node_kernel, dim3(BN / 4), dim3(256), 0, stream,
                     emb_node, Wn, bn, Wsn, bsn, node_x, rsx);
  hipLaunchKernelGGL(edge_mfma_kernel, dim3(BN), dim3(256), 0, stream,
                     A, emb_edge, We, be, node_x, rsx, node_out, edge_out);
}